// Round 1
// baseline (152.248 us; speedup 1.0000x reference)
//
#include <hip/hip_runtime.h>

// Problem constants
#define D_NODES 128
#define KD      128   // x feature dim (K of GEMM1)
#define M1_     256
#define M2_     128
#define B_      4096
#define BM      128   // batch rows per block
#define CI      64    // i-chunk of M1
#define NCH     4     // M1/CI

typedef short bf16x8  __attribute__((ext_vector_type(8)));  // 8 bf16 (4 VGPRs)
typedef short short4v __attribute__((ext_vector_type(4)));
typedef float f32x4   __attribute__((ext_vector_type(4)));

#define MFMA16(a, b, c) __builtin_amdgcn_mfma_f32_16x16x32_bf16((a), (b), (c), 0, 0, 0)

__device__ __forceinline__ short f2b(float f) {
  // fp32 -> bf16 round-to-nearest-even (bit trick)
  unsigned u = __builtin_bit_cast(unsigned, f);
  u += 0x7FFFu + ((u >> 16) & 1u);
  return (short)(u >> 16);
}

__device__ __forceinline__ float sigmoidf_(float x) {
  float e = __builtin_amdgcn_exp2f(-1.44269504088896f * x);
  return __builtin_amdgcn_rcpf(1.0f + e);
}

// ---- pre-pass kernels (fast path, run every launch; deterministic) ----
__global__ void cvt_f2b_k(const float* __restrict__ in, short* __restrict__ out) {
  int i = (blockIdx.x * 256 + threadIdx.x) * 4;
  float4 f = *(const float4*)(in + i);
  short4v s; s[0] = f2b(f.x); s[1] = f2b(f.y); s[2] = f2b(f.z); s[3] = f2b(f.w);
  *(short4v*)(out + i) = s;
}

// Wa [node][i=256][o=128] fp32  ->  waT [node][o=128][i=256] bf16
__global__ void trans_wa_k(const float* __restrict__ Wa, short* __restrict__ waT) {
  __shared__ float lt[64][129];   // +1 pad: conflict-free column reads
  int node = blockIdx.x >> 2, iblk = blockIdx.x & 3;
  int t = threadIdx.x;
  for (int j = 0; j < 32; ++j) {            // 64x128 coalesced load
    int e = j * 256 + t;
    int i = e >> 7, o = e & 127;
    lt[i][o] = Wa[(node * M1_ + iblk * 64 + i) * M2_ + o];
  }
  __syncthreads();
  int il = t & 63, ob = t >> 6;
  for (int j = 0; j < 32; ++j) {            // coalesced bf16 store along i
    int o = j * 4 + ob;
    waT[(node * M2_ + o) * M1_ + iblk * 64 + il] = f2b(lt[il][o]);
  }
}

// ---- fused main kernel ----
// FAST: weights/x pre-converted to bf16 in ws (w1b [32768][128], waT [128][128][256], xb [4096][128])
template <bool FAST>
__global__ __launch_bounds__(256, 2)
void fused_dag_k(const float* __restrict__ x,  const float* __restrict__ W1,
                 const float* __restrict__ b1, const float* __restrict__ Wa,
                 const float* __restrict__ ba, const float* __restrict__ Wb,
                 const float* __restrict__ bb, float* __restrict__ out,
                 const short* __restrict__ w1b, const short* __restrict__ waT,
                 const short* __restrict__ xb) {
  __shared__ __align__(16) short w1s[CI][136];   // [i][k], pad 272B rows
  __shared__ __align__(16) short wasT[M2_][72];  // [o][i-chunk], pad 144B rows
  __shared__ __align__(16) short h1s[BM][72];    // [b][i-chunk]
  __shared__ float partial[BM][2];

  // node-grouped XCD swizzle (locality heuristic only)
  int gid = blockIdx.x;
  int xcd = gid & 7, ii = gid >> 3;
  int node = xcd * 16 + (ii >> 5);
  int tile = ii & 31;
  int b0 = tile * BM;

  int t = threadIdx.x;
  int w = t >> 6, l = t & 63;
  int n = l & 15, q = l >> 4;

  // Preload x A-frags for GEMM1: wave w owns rows 32w..32w+31
  bf16x8 xa[2][4];
#pragma unroll
  for (int mt = 0; mt < 2; ++mt) {
#pragma unroll
    for (int kk = 0; kk < 4; ++kk) {
      int row = b0 + 32 * w + 16 * mt + n;
      int k0 = kk * 32 + q * 8;
      if (FAST) {
        xa[mt][kk] = *(const bf16x8*)(xb + row * KD + k0);
      } else {
        float4 f0 = *(const float4*)(x + row * KD + k0);
        float4 f1 = *(const float4*)(x + row * KD + k0 + 4);
        bf16x8 v;
        v[0] = f2b(f0.x); v[1] = f2b(f0.y); v[2] = f2b(f0.z); v[3] = f2b(f0.w);
        v[4] = f2b(f1.x); v[5] = f2b(f1.y); v[6] = f2b(f1.z); v[7] = f2b(f1.w);
        xa[mt][kk] = v;
      }
    }
  }

  f32x4 acc2[4][4];
#pragma unroll
  for (int a = 0; a < 4; ++a)
#pragma unroll
    for (int b = 0; b < 4; ++b) acc2[a][b] = (f32x4){0.f, 0.f, 0.f, 0.f};

  for (int c = 0; c < NCH; ++c) {
    __syncthreads();  // previous chunk's consumers done before restage
    int R0 = node * M1_ + c * CI;  // W1 row base for this node+chunk
    if (FAST) {
#pragma unroll
      for (int j = 0; j < 4; ++j) {  // w1s: 64x128 bf16, 16B chunks
        int ch = j * 256 + t;
        int r = ch >> 4, c8 = ch & 15;
        *(bf16x8*)(&w1s[r][c8 * 8]) = *(const bf16x8*)(w1b + (R0 + r) * KD + c8 * 8);
      }
#pragma unroll
      for (int j = 0; j < 4; ++j) {  // wasT: 128 rows x 64 i
        int ch = j * 256 + t;
        int r = ch >> 3, c8 = ch & 7;
        *(bf16x8*)(&wasT[r][c8 * 8]) =
            *(const bf16x8*)(waT + (node * M2_ + r) * M1_ + c * CI + c8 * 8);
      }
    } else {
#pragma unroll
      for (int j = 0; j < 8; ++j) {  // w1s from fp32
        int g = j * 256 + t;
        int r = g >> 5, c4 = g & 31;
        float4 f = *(const float4*)(W1 + (R0 + r) * KD + c4 * 4);
        short4v s; s[0] = f2b(f.x); s[1] = f2b(f.y); s[2] = f2b(f.z); s[3] = f2b(f.w);
        *(short4v*)(&w1s[r][c4 * 4]) = s;
      }
      for (int j = 0; j < 32; ++j) {  // wasT transpose from fp32 (slow fallback)
        int e = j * 256 + t;
        int o = e & 127, i = e >> 7;
        wasT[o][i] = f2b(Wa[(node * M1_ + c * CI + i) * M2_ + o]);
      }
    }
    __syncthreads();

    // GEMM1: h1c[32 rows x 64 i] per wave; B from w1s
    f32x4 acc1[2][4];
#pragma unroll
    for (int a = 0; a < 2; ++a)
#pragma unroll
      for (int b = 0; b < 4; ++b) acc1[a][b] = (f32x4){0.f, 0.f, 0.f, 0.f};
#pragma unroll
    for (int kk = 0; kk < 4; ++kk) {
      bf16x8 wb[4];
#pragma unroll
      for (int it = 0; it < 4; ++it)
        wb[it] = *(const bf16x8*)(&w1s[16 * it + n][kk * 32 + q * 8]);
#pragma unroll
      for (int mt = 0; mt < 2; ++mt)
#pragma unroll
        for (int it = 0; it < 4; ++it)
          acc1[mt][it] = MFMA16(xa[mt][kk], wb[it], acc1[mt][it]);
    }
    // bias + sigmoid -> h1s (bf16)
#pragma unroll
    for (int it = 0; it < 4; ++it) {
      float b1v = b1[node * M1_ + c * CI + 16 * it + n];
#pragma unroll
      for (int mt = 0; mt < 2; ++mt) {
        int rowb = 32 * w + 16 * mt + 4 * q;
#pragma unroll
        for (int r = 0; r < 4; ++r) {
          float s = sigmoidf_(acc1[mt][it][r] + b1v);
          h1s[rowb + r][16 * it + n] = f2b(s);
        }
      }
    }
    __syncthreads();

    // GEMM2: wave (w>>1 -> row half, w&1 -> o half), 64x64 tile, K=CI
    int R2 = 64 * (w >> 1), O2 = 64 * (w & 1);
#pragma unroll
    for (int kk = 0; kk < 2; ++kk) {
      bf16x8 ha[4], wa[4];
#pragma unroll
      for (int mt = 0; mt < 4; ++mt)
        ha[mt] = *(const bf16x8*)(&h1s[R2 + 16 * mt + n][kk * 32 + q * 8]);
#pragma unroll
      for (int ot = 0; ot < 4; ++ot)
        wa[ot] = *(const bf16x8*)(&wasT[O2 + 16 * ot + n][kk * 32 + q * 8]);
#pragma unroll
      for (int mt = 0; mt < 4; ++mt)
#pragma unroll
        for (int ot = 0; ot < 4; ++ot)
          acc2[mt][ot] = MFMA16(ha[mt], wa[ot], acc2[mt][ot]);
    }
  }

  // Epilogue: sigmoid(h2 + ba) * Wb, reduce over o
  int R2 = 64 * (w >> 1), O2 = 64 * (w & 1);
#pragma unroll
  for (int mt = 0; mt < 4; ++mt) {
    f32x4 rowsum = (f32x4){0.f, 0.f, 0.f, 0.f};
#pragma unroll
    for (int ot = 0; ot < 4; ++ot) {
      int o = O2 + 16 * ot + n;
      float bav = ba[node * M2_ + o];
      float wbv = Wb[node * M2_ + o];
#pragma unroll
      for (int r = 0; r < 4; ++r)
        rowsum[r] += sigmoidf_(acc2[mt][ot][r] + bav) * wbv;
    }
#pragma unroll
    for (int r = 0; r < 4; ++r) {
      float v = rowsum[r];
      v += __shfl_xor(v, 1);
      v += __shfl_xor(v, 2);
      v += __shfl_xor(v, 4);
      v += __shfl_xor(v, 8);
      if (n == 0) partial[R2 + 16 * mt + 4 * q + r][w & 1] = v;
    }
  }
  __syncthreads();
  if (t < BM) {
    out[(size_t)(b0 + t) * D_NODES + node] = partial[t][0] + partial[t][1] + bb[node];
  }
}

extern "C" void kernel_launch(void* const* d_in, const int* in_sizes, int n_in,
                              void* d_out, int out_size, void* d_ws, size_t ws_size,
                              hipStream_t stream) {
  const float* x  = (const float*)d_in[0];
  const float* W1 = (const float*)d_in[1];
  const float* b1 = (const float*)d_in[2];
  const float* Wa = (const float*)d_in[3];
  const float* ba = (const float*)d_in[4];
  const float* Wb = (const float*)d_in[5];
  const float* bb = (const float*)d_in[6];
  float* out = (float*)d_out;

  const size_t W1_ELEMS = (size_t)D_NODES * M1_ * KD;   // 4194304
  const size_t WA_ELEMS = (size_t)D_NODES * M1_ * M2_;  // 4194304
  const size_t X_ELEMS  = (size_t)B_ * KD;              // 524288
  const size_t NEED = (W1_ELEMS + WA_ELEMS + X_ELEMS) * sizeof(short);

  if (ws_size >= NEED) {
    short* w1b = (short*)d_ws;
    short* waT = w1b + W1_ELEMS;
    short* xb  = waT + WA_ELEMS;
    cvt_f2b_k<<<(int)(W1_ELEMS / 1024), 256, 0, stream>>>(W1, w1b);
    cvt_f2b_k<<<(int)(X_ELEMS / 1024), 256, 0, stream>>>(x, xb);
    trans_wa_k<<<D_NODES * 4, 256, 0, stream>>>(Wa, waT);
    fused_dag_k<true><<<4096, 256, 0, stream>>>(x, W1, b1, Wa, ba, Wb, bb, out, w1b, waT, xb);
  } else {
    fused_dag_k<false><<<4096, 256, 0, stream>>>(x, W1, b1, Wa, ba, Wb, bb, out,
                                                 nullptr, nullptr, nullptr);
  }
}

// Round 2
// 142.722 us; speedup vs baseline: 1.0667x; 1.0667x over previous
//
#include <hip/hip_runtime.h>

// Problem constants
#define D_NODES 128
#define KD      128   // x feature dim (K of GEMM1)
#define M1_     256
#define M2_     128
#define B_      4096
#define BM      128   // batch rows per block
#define CI      64    // i-chunk of M1
#define NCH     4     // M1/CI

typedef short bf16x8  __attribute__((ext_vector_type(8)));  // 8 bf16 (4 VGPRs)
typedef short short4v __attribute__((ext_vector_type(4)));
typedef float f32x4   __attribute__((ext_vector_type(4)));

#define MFMA16(a, b, c) __builtin_amdgcn_mfma_f32_16x16x32_bf16((a), (b), (c), 0, 0, 0)

__device__ __forceinline__ short f2b(float f) {
  unsigned u = __builtin_bit_cast(unsigned, f);
  u += 0x7FFFu + ((u >> 16) & 1u);
  return (short)(u >> 16);
}

__device__ __forceinline__ float sigmoidf_(float x) {
  float e = __builtin_amdgcn_exp2f(-1.44269504088896f * x);
  return __builtin_amdgcn_rcpf(1.0f + e);
}

// ---- pre-pass kernels ----
__global__ void cvt_f2b_k(const float* __restrict__ in, short* __restrict__ out) {
  int i = (blockIdx.x * 256 + threadIdx.x) * 4;
  float4 f = *(const float4*)(in + i);
  short4v s; s[0] = f2b(f.x); s[1] = f2b(f.y); s[2] = f2b(f.z); s[3] = f2b(f.w);
  *(short4v*)(out + i) = s;
}

// Wa [node][i=256][o=128] fp32 -> waT [node][o=128][i=256] bf16
__global__ void trans_wa_k(const float* __restrict__ Wa, short* __restrict__ waT) {
  __shared__ float lt[64][129];
  int node = blockIdx.x >> 2, iblk = blockIdx.x & 3;
  int t = threadIdx.x;
  for (int j = 0; j < 32; ++j) {
    int e = j * 256 + t;
    int i = e >> 7, o = e & 127;
    lt[i][o] = Wa[(node * M1_ + iblk * 64 + i) * M2_ + o];
  }
  __syncthreads();
  int il = t & 63, ob = t >> 6;
  for (int j = 0; j < 32; ++j) {
    int o = j * 4 + ob;
    waT[(node * M2_ + o) * M1_ + iblk * 64 + il] = f2b(lt[il][o]);
  }
}

// ---- fused main kernel ----
// GEMM1 computes h1T (A=W1, B=x) so each lane holds 4 consecutive-i values
// at fixed b -> packed ds_write_b64 into h1s[b][i] (bank-minimal).
// 512 threads (8 waves), launch_bounds(512,4) -> VGPR<=128 -> 16 waves/CU.
template <bool FAST>
__global__ __launch_bounds__(512, 4)
void fused_dag_k(const float* __restrict__ x,  const float* __restrict__ W1,
                 const float* __restrict__ b1, const float* __restrict__ Wa,
                 const float* __restrict__ ba, const float* __restrict__ Wb,
                 const float* __restrict__ bb, float* __restrict__ out,
                 const short* __restrict__ w1b, const short* __restrict__ waT,
                 const short* __restrict__ xb) {
  __shared__ __align__(16) short w1s[CI][136];   // [i][k] pad: 272B rows
  __shared__ __align__(16) short wasT[M2_][72];  // [o][i-chunk] pad: 144B rows
  __shared__ __align__(16) short h1s[BM][72];    // [b][i-chunk] pad: 144B rows
  __shared__ float partial[BM][2];

  int gid = blockIdx.x;
  int xcd = gid & 7, ii = gid >> 3;
  int node = xcd * 16 + (ii >> 5);
  int tile = ii & 31;
  int b0 = tile * BM;

  int t = threadIdx.x;
  int w = t >> 6, l = t & 63;
  int n = l & 15, q = l >> 4;

  // x B-frags: wave w owns batch rows [16w, 16w+16); lane's row = 16w+n
  bf16x8 xa[4];
  {
    int row = b0 + 16 * w + n;
#pragma unroll
    for (int kk = 0; kk < 4; ++kk) {
      int k0 = kk * 32 + q * 8;
      if (FAST) {
        xa[kk] = *(const bf16x8*)(xb + row * KD + k0);
      } else {
        float4 f0 = *(const float4*)(x + row * KD + k0);
        float4 f1 = *(const float4*)(x + row * KD + k0 + 4);
        bf16x8 v;
        v[0] = f2b(f0.x); v[1] = f2b(f0.y); v[2] = f2b(f0.z); v[3] = f2b(f0.w);
        v[4] = f2b(f1.x); v[5] = f2b(f1.y); v[6] = f2b(f1.z); v[7] = f2b(f1.w);
        xa[kk] = v;
      }
    }
  }

  f32x4 acc2[2][4];
#pragma unroll
  for (int a = 0; a < 2; ++a)
#pragma unroll
    for (int b = 0; b < 4; ++b) acc2[a][b] = (f32x4){0.f, 0.f, 0.f, 0.f};

  for (int c = 0; c < NCH; ++c) {
    __syncthreads();  // prev chunk's GEMM1/GEMM2 reads done before restage
    int R0 = node * M1_ + c * CI;
    if (FAST) {
#pragma unroll
      for (int j = 0; j < 2; ++j) {  // w1s: 64 rows x 16 chunks of 8 bf16
        int ch = j * 512 + t;
        int r = ch >> 4, c8 = ch & 15;
        *(bf16x8*)(&w1s[r][c8 * 8]) = *(const bf16x8*)(w1b + (R0 + r) * KD + c8 * 8);
      }
#pragma unroll
      for (int j = 0; j < 2; ++j) {  // wasT: 128 rows x 8 chunks
        int ch = j * 512 + t;
        int r = ch >> 3, c8 = ch & 7;
        *(bf16x8*)(&wasT[r][c8 * 8]) =
            *(const bf16x8*)(waT + (node * M2_ + r) * M1_ + c * CI + c8 * 8);
      }
    } else {
#pragma unroll
      for (int j = 0; j < 4; ++j) {
        int g = j * 512 + t;
        int r = g >> 5, c4 = g & 31;
        float4 f = *(const float4*)(W1 + (R0 + r) * KD + c4 * 4);
        short4v s; s[0] = f2b(f.x); s[1] = f2b(f.y); s[2] = f2b(f.z); s[3] = f2b(f.w);
        *(short4v*)(&w1s[r][c4 * 4]) = s;
      }
      for (int j = 0; j < 16; ++j) {
        int e = j * 512 + t;
        int o = e & 127, i = e >> 7;
        wasT[o][i] = f2b(Wa[(node * M1_ + c * CI + i) * M2_ + o]);
      }
    }
    __syncthreads();

    // GEMM1: C1T[i=64][b=16 per wave] ; A = w1s rows (i), B = xa (b)
    f32x4 acc1[4];
#pragma unroll
    for (int a = 0; a < 4; ++a) acc1[a] = (f32x4){0.f, 0.f, 0.f, 0.f};
#pragma unroll
    for (int kk = 0; kk < 4; ++kk) {
      bf16x8 wf[4];
#pragma unroll
      for (int it = 0; it < 4; ++it)
        wf[it] = *(const bf16x8*)(&w1s[16 * it + n][kk * 32 + q * 8]);
#pragma unroll
      for (int it = 0; it < 4; ++it)
        acc1[it] = MFMA16(wf[it], xa[kk], acc1[it]);
    }
    // bias + sigmoid + packed b64 write: lane holds h1[b=16w+n][i=16it+4q+r]
#pragma unroll
    for (int it = 0; it < 4; ++it) {
      f32x4 b1v = *(const f32x4*)(b1 + node * M1_ + c * CI + 16 * it + 4 * q);
      short4v s;
#pragma unroll
      for (int r = 0; r < 4; ++r)
        s[r] = f2b(sigmoidf_(acc1[it][r] + b1v[r]));
      *(short4v*)(&h1s[16 * w + n][16 * it + 4 * q]) = s;
    }
    __syncthreads();

    // GEMM2: wave -> rows R2=32*(w&3), o-half O2=64*(w>>2); K = CI
    int R2 = 32 * (w & 3), O2 = 64 * (w >> 2);
#pragma unroll
    for (int kk = 0; kk < 2; ++kk) {
      bf16x8 ha[2], wa[4];
#pragma unroll
      for (int mt = 0; mt < 2; ++mt)
        ha[mt] = *(const bf16x8*)(&h1s[R2 + 16 * mt + n][kk * 32 + q * 8]);
#pragma unroll
      for (int ot = 0; ot < 4; ++ot)
        wa[ot] = *(const bf16x8*)(&wasT[O2 + 16 * ot + n][kk * 32 + q * 8]);
#pragma unroll
      for (int mt = 0; mt < 2; ++mt)
#pragma unroll
        for (int ot = 0; ot < 4; ++ot)
          acc2[mt][ot] = MFMA16(ha[mt], wa[ot], acc2[mt][ot]);
    }
  }

  // Epilogue: sigmoid(h2 + ba) * Wb, reduce over o
  int R2 = 32 * (w & 3), O2 = 64 * (w >> 2);
#pragma unroll
  for (int mt = 0; mt < 2; ++mt) {
    f32x4 rowsum = (f32x4){0.f, 0.f, 0.f, 0.f};
#pragma unroll
    for (int ot = 0; ot < 4; ++ot) {
      int o = O2 + 16 * ot + n;
      float bav = ba[node * M2_ + o];
      float wbv = Wb[node * M2_ + o];
#pragma unroll
      for (int r = 0; r < 4; ++r)
        rowsum[r] += sigmoidf_(acc2[mt][ot][r] + bav) * wbv;
    }
#pragma unroll
    for (int r = 0; r < 4; ++r) {
      float v = rowsum[r];
      v += __shfl_xor(v, 1);
      v += __shfl_xor(v, 2);
      v += __shfl_xor(v, 4);
      v += __shfl_xor(v, 8);
      if (n == 0) partial[R2 + 16 * mt + 4 * q + r][w >> 2] = v;
    }
  }
  __syncthreads();
  if (t < BM) {
    out[(size_t)(b0 + t) * D_NODES + node] = partial[t][0] + partial[t][1] + bb[node];
  }
}

extern "C" void kernel_launch(void* const* d_in, const int* in_sizes, int n_in,
                              void* d_out, int out_size, void* d_ws, size_t ws_size,
                              hipStream_t stream) {
  const float* x  = (const float*)d_in[0];
  const float* W1 = (const float*)d_in[1];
  const float* b1 = (const float*)d_in[2];
  const float* Wa = (const float*)d_in[3];
  const float* ba = (const float*)d_in[4];
  const float* Wb = (const float*)d_in[5];
  const float* bb = (const float*)d_in[6];
  float* out = (float*)d_out;

  const size_t W1_ELEMS = (size_t)D_NODES * M1_ * KD;   // 4194304
  const size_t WA_ELEMS = (size_t)D_NODES * M1_ * M2_;  // 4194304
  const size_t X_ELEMS  = (size_t)B_ * KD;              // 524288
  const size_t NEED = (W1_ELEMS + WA_ELEMS + X_ELEMS) * sizeof(short);

  if (ws_size >= NEED) {
    short* w1b = (short*)d_ws;
    short* waT = w1b + W1_ELEMS;
    short* xb  = waT + WA_ELEMS;
    cvt_f2b_k<<<(int)(W1_ELEMS / 1024), 256, 0, stream>>>(W1, w1b);
    cvt_f2b_k<<<(int)(X_ELEMS / 1024), 256, 0, stream>>>(x, xb);
    trans_wa_k<<<D_NODES * 4, 256, 0, stream>>>(Wa, waT);
    fused_dag_k<true><<<4096, 512, 0, stream>>>(x, W1, b1, Wa, ba, Wb, bb, out, w1b, waT, xb);
  } else {
    fused_dag_k<false><<<4096, 512, 0, stream>>>(x, W1, b1, Wa, ba, Wb, bb, out,
                                                 nullptr, nullptr, nullptr);
  }
}

// Round 3
// 128.519 us; speedup vs baseline: 1.1846x; 1.1105x over previous
//
#include <hip/hip_runtime.h>

// Problem constants
#define D_NODES 128
#define KD      128   // x feature dim (K of GEMM1)
#define M1_     256
#define M2_     128
#define B_      4096
#define BM      256   // batch rows per block
#define WROWS   32    // rows per wave (2 m-tiles of 16)
#define CI      64    // i-chunk of M1
#define NCH     4     // M1/CI

typedef short bf16x8  __attribute__((ext_vector_type(8)));  // 8 bf16 (4 VGPRs)
typedef short short4v __attribute__((ext_vector_type(4)));
typedef float f32x4   __attribute__((ext_vector_type(4)));

#define MFMA16(a, b, c) __builtin_amdgcn_mfma_f32_16x16x32_bf16((a), (b), (c), 0, 0, 0)

__device__ __forceinline__ short f2b(float f) {
  unsigned u = __builtin_bit_cast(unsigned, f);
  u += 0x7FFFu + ((u >> 16) & 1u);
  return (short)(u >> 16);
}

__device__ __forceinline__ float sigmoidf_(float x) {
  float e = __builtin_amdgcn_exp2f(-1.44269504088896f * x);
  return __builtin_amdgcn_rcpf(1.0f + e);
}

// ---- pre-pass kernels ----
__global__ void cvt_f2b_k(const float* __restrict__ in, short* __restrict__ out) {
  int i = (blockIdx.x * 256 + threadIdx.x) * 4;
  float4 f = *(const float4*)(in + i);
  short4v s; s[0] = f2b(f.x); s[1] = f2b(f.y); s[2] = f2b(f.z); s[3] = f2b(f.w);
  *(short4v*)(out + i) = s;
}

// Wa [node][i=256][o=128] fp32 -> waT [node][o=128][i=256] bf16
__global__ void trans_wa_k(const float* __restrict__ Wa, short* __restrict__ waT) {
  __shared__ float lt[64][129];
  int node = blockIdx.x >> 2, iblk = blockIdx.x & 3;
  int t = threadIdx.x;
  for (int j = 0; j < 32; ++j) {
    int e = j * 256 + t;
    int i = e >> 7, o = e & 127;
    lt[i][o] = Wa[(node * M1_ + iblk * 64 + i) * M2_ + o];
  }
  __syncthreads();
  int il = t & 63, ob = t >> 6;
  for (int j = 0; j < 32; ++j) {
    int o = j * 4 + ob;
    waT[(node * M2_ + o) * M1_ + iblk * 64 + il] = f2b(lt[il][o]);
  }
}

// ---- fused main kernel ----
// Barrier-free after a single staging sync: full per-node W1 (64KB) + WaT
// (64KB) live in LDS, XOR-swizzled at 16B granules (g ^= row&7) so every
// b128 read/b64 write spreads uniformly over banks. Each wave owns 32 batch
// rows end-to-end; h1 exchange is within-wave via a private LDS buffer
// (lgkmcnt only, no __syncthreads in the main loop).
template <bool FAST>
__global__ __launch_bounds__(512, 2)
void fused_dag_k(const float* __restrict__ x,  const float* __restrict__ W1,
                 const float* __restrict__ b1, const float* __restrict__ Wa,
                 const float* __restrict__ ba, const float* __restrict__ Wb,
                 const float* __restrict__ bb, float* __restrict__ out,
                 const short* __restrict__ w1b, const short* __restrict__ waT,
                 const short* __restrict__ xb) {
  __shared__ __align__(16) short w1s[M1_ * KD];     // [i=256][k=128] swizzled, 64KB
  __shared__ __align__(16) short was[M2_ * M1_];    // [o=128][k=256] swizzled, 64KB
  __shared__ __align__(16) short h1w[8 * 16 * CI];  // per-wave [16][64] swizzled, 16KB

  int gid = blockIdx.x;                 // 2048 blocks = 128 nodes x 8 tiles... (16 tiles)
  int xcd = gid & 7, ii = gid >> 3;     // ii 0..255
  int node = xcd * 16 + (ii >> 4);      // nodes grouped per XCD for L2 reuse
  int tile = ii & 15;
  int b0 = tile * BM;

  int t = threadIdx.x;
  int w = t >> 6, l = t & 63;
  int n15 = l & 15, q = l >> 4;

  // ---- stage weights (reg-staged: linear coalesced load, swizzled ds_write) ----
  if (FAST) {
    const short* w1n = w1b + (size_t)node * M1_ * KD;
    const short* wan = waT + (size_t)node * M2_ * M1_;
    bf16x8 t1[8], t2[8];
#pragma unroll
    for (int j = 0; j < 8; ++j) t1[j] = *(const bf16x8*)(w1n + (j * 512 + t) * 8);
#pragma unroll
    for (int j = 0; j < 8; ++j) t2[j] = *(const bf16x8*)(wan + (j * 512 + t) * 8);
#pragma unroll
    for (int j = 0; j < 8; ++j) {
      int s = j * 512 + t;
      int row = s >> 4, g = s & 15;      // 16 granules per 128-k row
      *(bf16x8*)(&w1s[row * KD + ((g ^ (row & 7)) << 3)]) = t1[j];
    }
#pragma unroll
    for (int j = 0; j < 8; ++j) {
      int s = j * 512 + t;
      int row = s >> 5, g = s & 31;      // 32 granules per 256-k row
      *(bf16x8*)(&was[row * M1_ + ((g ^ (row & 7)) << 3)]) = t2[j];
    }
  } else {
#pragma unroll
    for (int j = 0; j < 8; ++j) {
      int s = j * 512 + t;
      int row = s >> 4, g = s & 15;
      const float* src = W1 + ((size_t)node * M1_ + row) * KD + g * 8;
      float4 f0 = *(const float4*)(src);
      float4 f1 = *(const float4*)(src + 4);
      bf16x8 v;
      v[0] = f2b(f0.x); v[1] = f2b(f0.y); v[2] = f2b(f0.z); v[3] = f2b(f0.w);
      v[4] = f2b(f1.x); v[5] = f2b(f1.y); v[6] = f2b(f1.z); v[7] = f2b(f1.w);
      *(bf16x8*)(&w1s[row * KD + ((g ^ (row & 7)) << 3)]) = v;
    }
    for (int j = 0; j < 8; ++j) {
      int s = j * 512 + t;
      int o = s >> 5, g = s & 31;
      bf16x8 v;
#pragma unroll
      for (int e = 0; e < 8; ++e)
        v[e] = f2b(Wa[((size_t)node * M1_ + g * 8 + e) * M2_ + o]);
      *(bf16x8*)(&was[o * M1_ + ((g ^ (o & 7)) << 3)]) = v;
    }
  }

  // x B-frags for this wave's 32 rows (2 m-tiles of 16)
  bf16x8 xa[2][4];
  {
    int rb = b0 + w * WROWS;
#pragma unroll
    for (int mt = 0; mt < 2; ++mt) {
      int row = rb + mt * 16 + n15;
#pragma unroll
      for (int kk = 0; kk < 4; ++kk) {
        int k0 = kk * 32 + q * 8;
        if (FAST) {
          xa[mt][kk] = *(const bf16x8*)(xb + row * KD + k0);
        } else {
          float4 f0 = *(const float4*)(x + row * KD + k0);
          float4 f1 = *(const float4*)(x + row * KD + k0 + 4);
          bf16x8 v;
          v[0] = f2b(f0.x); v[1] = f2b(f0.y); v[2] = f2b(f0.z); v[3] = f2b(f0.w);
          v[4] = f2b(f1.x); v[5] = f2b(f1.y); v[6] = f2b(f1.z); v[7] = f2b(f1.w);
          xa[mt][kk] = v;
        }
      }
    }
  }

  __syncthreads();  // the ONLY barrier: staged weights visible to all waves

  f32x4 acc2[2][8];  // [mt][ot]: C2[32 rows][128 o]
#pragma unroll
  for (int a = 0; a < 2; ++a)
#pragma unroll
    for (int b = 0; b < 8; ++b) acc2[a][b] = (f32x4){0.f, 0.f, 0.f, 0.f};

  short* myh1 = &h1w[w * 16 * CI];  // private [16][64] swizzled
  int swz = n15 & 7;

  for (int c = 0; c < NCH; ++c) {
    // GEMM1: C1[i=64][b=32]; A = W1 rows (i), B = xa
    f32x4 acc1[4][2];
#pragma unroll
    for (int a = 0; a < 4; ++a)
#pragma unroll
      for (int b = 0; b < 2; ++b) acc1[a][b] = (f32x4){0.f, 0.f, 0.f, 0.f};
#pragma unroll
    for (int kk = 0; kk < 4; ++kk) {
      int gsw = (4 * kk + q) ^ swz;
#pragma unroll
      for (int it = 0; it < 4; ++it) {
        int row = c * CI + it * 16 + n15;
        bf16x8 wf = *(const bf16x8*)(&w1s[row * KD + (gsw << 3)]);
        acc1[it][0] = MFMA16(wf, xa[0][kk], acc1[it][0]);
        acc1[it][1] = MFMA16(wf, xa[1][kk], acc1[it][1]);
      }
    }

    // WaT B-frags for this chunk's k-slice (shared across both m-tiles)
    bf16x8 wa[8][2];
#pragma unroll
    for (int ot = 0; ot < 8; ++ot) {
      int o = ot * 16 + n15;
#pragma unroll
      for (int kk = 0; kk < 2; ++kk) {
        int g = (c * 8 + kk * 4 + q) ^ swz;
        wa[ot][kk] = *(const bf16x8*)(&was[o * M1_ + (g << 3)]);
      }
    }

    const float* b1c = b1 + node * M1_ + c * CI;
#pragma unroll
    for (int mt = 0; mt < 2; ++mt) {
      // bias + sigmoid + packed b64 write: lane holds C1[i=16it+4q+r][b=16mt+n15]
#pragma unroll
      for (int it = 0; it < 4; ++it) {
        f32x4 bv = *(const f32x4*)(b1c + it * 16 + q * 4);
        short4v s4;
#pragma unroll
        for (int r = 0; r < 4; ++r)
          s4[r] = f2b(sigmoidf_(acc1[it][mt][r] + bv[r]));
        int gi = (2 * it + (q >> 1)) ^ swz;
        *(short4v*)(&myh1[n15 * CI + (gi << 3) + (q & 1) * 4]) = s4;
      }
      // within-wave readback (lgkmcnt only) + GEMM2 accumulate
#pragma unroll
      for (int kk = 0; kk < 2; ++kk) {
        int g = (4 * kk + q) ^ swz;
        bf16x8 ha = *(const bf16x8*)(&myh1[n15 * CI + (g << 3)]);
#pragma unroll
        for (int ot = 0; ot < 8; ++ot)
          acc2[mt][ot] = MFMA16(ha, wa[ot][kk], acc2[mt][ot]);
      }
    }
  }

  // Epilogue: sigmoid(h2 + ba) * Wb, reduce over o within wave, store
  const float* ban = ba + node * M2_;
  const float* wbn = Wb + node * M2_;
  float bbv = bb[node];
#pragma unroll
  for (int mt = 0; mt < 2; ++mt) {
    f32x4 rs = (f32x4){0.f, 0.f, 0.f, 0.f};
#pragma unroll
    for (int ot = 0; ot < 8; ++ot) {
      int o = ot * 16 + n15;
      float bav = ban[o];
      float wbv = wbn[o];
#pragma unroll
      for (int r = 0; r < 4; ++r)
        rs[r] += sigmoidf_(acc2[mt][ot][r] + bav) * wbv;
    }
#pragma unroll
    for (int r = 0; r < 4; ++r) {
      float v = rs[r];
      v += __shfl_xor(v, 1);
      v += __shfl_xor(v, 2);
      v += __shfl_xor(v, 4);
      v += __shfl_xor(v, 8);
      if (n15 == 0)
        out[(size_t)(b0 + w * WROWS + mt * 16 + q * 4 + r) * D_NODES + node] = v + bbv;
    }
  }
}

extern "C" void kernel_launch(void* const* d_in, const int* in_sizes, int n_in,
                              void* d_out, int out_size, void* d_ws, size_t ws_size,
                              hipStream_t stream) {
  const float* x  = (const float*)d_in[0];
  const float* W1 = (const float*)d_in[1];
  const float* b1 = (const float*)d_in[2];
  const float* Wa = (const float*)d_in[3];
  const float* ba = (const float*)d_in[4];
  const float* Wb = (const float*)d_in[5];
  const float* bb = (const float*)d_in[6];
  float* out = (float*)d_out;

  const size_t W1_ELEMS = (size_t)D_NODES * M1_ * KD;   // 4194304
  const size_t WA_ELEMS = (size_t)D_NODES * M1_ * M2_;  // 4194304
  const size_t X_ELEMS  = (size_t)B_ * KD;              // 524288
  const size_t NEED = (W1_ELEMS + WA_ELEMS + X_ELEMS) * sizeof(short);

  const int GRID = D_NODES * (B_ / BM);  // 2048

  if (ws_size >= NEED) {
    short* w1b = (short*)d_ws;
    short* waT = w1b + W1_ELEMS;
    short* xb  = waT + WA_ELEMS;
    cvt_f2b_k<<<(int)(W1_ELEMS / 1024), 256, 0, stream>>>(W1, w1b);
    cvt_f2b_k<<<(int)(X_ELEMS / 1024), 256, 0, stream>>>(x, xb);
    trans_wa_k<<<D_NODES * 4, 256, 0, stream>>>(Wa, waT);
    fused_dag_k<true><<<GRID, 512, 0, stream>>>(x, W1, b1, Wa, ba, Wb, bb, out, w1b, waT, xb);
  } else {
    fused_dag_k<false><<<GRID, 512, 0, stream>>>(x, W1, b1, Wa, ba, Wb, bb, out,
                                                 nullptr, nullptr, nullptr);
  }
}